// Round 1
// baseline (130333.240 us; speedup 1.0000x reference)
//
#include <hip/hip_runtime.h>
#include <hip/hip_fp16.h>

typedef unsigned int u32;

#define TSTEPS 2048
#define HID    1024
#define NDEPTH 5
#define GSTAGE 51
#define NBLOCKS (NDEPTH * GSTAGE)   // 255 blocks, 1 per CU

typedef _Float16 f16x2 __attribute__((ext_vector_type(2)));

#if defined(__has_builtin)
# if __has_builtin(__builtin_amdgcn_fdot2)
#  define HAVE_FDOT2 1
# endif
#endif

__device__ __forceinline__ float fdot2f(u32 a, u32 b, float c) {
  f16x2 x, y;
  __builtin_memcpy(&x, &a, 4);
  __builtin_memcpy(&y, &b, 4);
#ifdef HAVE_FDOT2
  return __builtin_amdgcn_fdot2(x, y, c, false);
#else
  return c + (float)x[0] * (float)y[0] + (float)x[1] * (float)y[1];
#endif
}

__device__ __forceinline__ u32 pkh(float a, float b) {
  __half2 h = __floats2half2_rn(a, b);
  u32 r;
  __builtin_memcpy(&r, &h, 4);
  return r;
}

// sum within each 32-lane half; valid in lanes 31 and 63
__device__ __forceinline__ float dpp_red32(float v) {
  int t, vi;
  __builtin_memcpy(&vi, &v, 4);
  float tf;
#define STEP(CTRL)                                                        \
  t = __builtin_amdgcn_update_dpp(0, vi, CTRL, 0xF, 0xF, true);           \
  __builtin_memcpy(&tf, &t, 4);                                           \
  v += tf;                                                                \
  __builtin_memcpy(&vi, &v, 4);
  STEP(0x111) // row_shr:1
  STEP(0x112) // row_shr:2
  STEP(0x114) // row_shr:4
  STEP(0x118) // row_shr:8
  STEP(0x142) // row_bcast:15
#undef STEP
  return v;
}

__device__ __forceinline__ void spin_flag(int* p, int target, bool do_sleep) {
  while (__hip_atomic_load(p, __ATOMIC_ACQUIRE, __HIP_MEMORY_SCOPE_AGENT) < target) {
    if (do_sleep) __builtin_amdgcn_s_sleep(1);
  }
}

// ---------------------------------------------------------------------------
// lin1: pre[t][h] = lines[t] . w1[h] + b1[h]   (lines built from x shifts)
// ---------------------------------------------------------------------------
__global__ __launch_bounds__(256) void lin1_kernel(
    const float* __restrict__ x, const float* __restrict__ w1,
    const float* __restrict__ b1, float* __restrict__ X0) {
  __shared__ float lt[32][65];
  __shared__ float wt[128][65];
  const int tid = threadIdx.x;
  const int t0 = blockIdx.x * 32;
  const int h0 = blockIdx.y * 128;
  const int tt0 = (tid & 7) * 4;
  const int hh0 = (tid >> 3) * 4;
  float acc[4][4] = {};
  for (int kc = 0; kc < 512; kc += 64) {
    __syncthreads();
#pragma unroll
    for (int m = 0; m < 8; ++m) {
      int e = tid + m * 256;
      int tt = e >> 6, kk = e & 63;
      int k = kc + kk;
      int a = k >> 5, io = k & 31;
      int d = (a == 0) ? 0 : (a + 1);
      int st = t0 + tt - d;
      lt[tt][kk] = (st >= 0) ? x[st * 32 + io] : 0.f;
    }
#pragma unroll
    for (int m = 0; m < 32; ++m) {
      int e = tid + m * 256;
      int hh = e >> 6, kk = e & 63;
      wt[hh][kk] = w1[(size_t)(h0 + hh) * 512 + kc + kk];
    }
    __syncthreads();
    for (int kk = 0; kk < 64; ++kk) {
      float la[4], wa[4];
#pragma unroll
      for (int i = 0; i < 4; ++i) la[i] = lt[tt0 + i][kk];
#pragma unroll
      for (int j = 0; j < 4; ++j) wa[j] = wt[hh0 + j][kk];
#pragma unroll
      for (int i = 0; i < 4; ++i)
#pragma unroll
        for (int j = 0; j < 4; ++j) acc[i][j] = fmaf(la[i], wa[j], acc[i][j]);
    }
  }
#pragma unroll
  for (int i = 0; i < 4; ++i)
#pragma unroll
    for (int j = 0; j < 4; ++j)
      X0[(size_t)(t0 + tt0 + i) * HID + h0 + hh0 + j] =
          acc[i][j] + b1[h0 + hh0 + j];
}

// ---------------------------------------------------------------------------
// persistent pipelined GRU: 5 stages x 51 blocks, weights fp16 in VGPRs
// ---------------------------------------------------------------------------
__global__ __launch_bounds__(1024) void gru_pipe(
    const float* __restrict__ wih, const float* __restrict__ whh,
    const float* __restrict__ bih, const float* __restrict__ bhh,
    float* __restrict__ X, int* __restrict__ flags) {
  const int bid = blockIdx.x;
  const int l   = bid / GSTAGE;
  const int bs  = bid % GSTAGE;
  const int tid = (int)threadIdx.x;
  const int lane = tid & 63;
  const int wv   = tid >> 6;
  const int half = lane >> 5;
  const int kc   = lane & 31;
  const bool is_gi = (wv < 8);
  const int rg = 2 * (wv & 7) + half;   // 0..15 row-group within gi or gh set

  const int h_base = (bs * HID) / GSTAGE;
  const int h_cnt  = ((bs + 1) * HID) / GSTAGE - h_base;
  const int ndot = 3 * h_cnt;

  const float* mat = (is_gi ? wih : whh) + (size_t)l * 3 * HID * HID;

  // 4 rows x 32 k-values of fp16 weights, packed 2/VGPR (64 regs)
  u32 wreg[4][16];
#pragma unroll
  for (int r = 0; r < 4; ++r) {
    const int d = 4 * rg + r;
    if (d < ndot) {
      const int jj = d / 3, g = d % 3;
      const float4* src =
          (const float4*)(mat + (size_t)(g * HID + h_base + jj) * HID + kc * 32);
#pragma unroll
      for (int i = 0; i < 8; ++i) {
        float4 f = src[i];
        wreg[r][2 * i]     = pkh(f.x, f.y);
        wreg[r][2 * i + 1] = pkh(f.z, f.w);
      }
    } else {
#pragma unroll
      for (int i = 0; i < 16; ++i) wreg[r][i] = 0u;
    }
  }

  float b6[6] = {0.f, 0.f, 0.f, 0.f, 0.f, 0.f};
  if (wv == 0 && lane < h_cnt) {
#pragma unroll
    for (int g = 0; g < 3; ++g) {
      b6[g]     = bih[(size_t)l * 3 * HID + g * HID + h_base + lane];
      b6[3 + g] = bhh[(size_t)l * 3 * HID + g * HID + h_base + lane];
    }
  }

  __shared__ __align__(16) __half xbuf[2][HID];
  __shared__ __align__(16) __half hbuf[2][HID];
  __shared__ __align__(16) float scr[2][128];
  __shared__ int ctr_gi, ctr_gh;
  if (tid == 0) { ctr_gi = 0; ctr_gh = 0; }
  __syncthreads();

  const float* Xin = X + (size_t)l * TSTEPS * HID;
  float* Xout      = X + (size_t)(l + 1) * TSTEPS * HID;
  int* f_in  = flags + l * TSTEPS;
  int* f_out = flags + (l + 1) * TSTEPS;

  for (int t = 0; t < TSTEPS; ++t) {
    const int p = t & 1;
    if (is_gi) {
      if (l > 0) spin_flag(&f_in[t], GSTAGE, true);
      // stage x_t -> fp16 LDS (atomic loads: always-fresh via LLC)
      float va = __hip_atomic_load((float*)(Xin + (size_t)t * HID + 2 * tid),
                                   __ATOMIC_RELAXED, __HIP_MEMORY_SCOPE_AGENT);
      float vb = __hip_atomic_load((float*)(Xin + (size_t)t * HID + 2 * tid + 1),
                                   __ATOMIC_RELAXED, __HIP_MEMORY_SCOPE_AGENT);
      ((u32*)xbuf[p])[tid] = pkh(va, vb);
      if (lane == 0)
        __hip_atomic_fetch_add(&ctr_gi, 1, __ATOMIC_RELEASE, __HIP_MEMORY_SCOPE_WORKGROUP);
      while (__hip_atomic_load(&ctr_gi, __ATOMIC_ACQUIRE, __HIP_MEMORY_SCOPE_WORKGROUP) <
             8 * (t + 1)) { }
    } else {
      const int tz = tid - 512;
      if (t > 0) {
        spin_flag(&f_out[t - 1], GSTAGE, false);
        float va = __hip_atomic_load((float*)(Xout + (size_t)(t - 1) * HID + 2 * tz),
                                     __ATOMIC_RELAXED, __HIP_MEMORY_SCOPE_AGENT);
        float vb = __hip_atomic_load((float*)(Xout + (size_t)(t - 1) * HID + 2 * tz + 1),
                                     __ATOMIC_RELAXED, __HIP_MEMORY_SCOPE_AGENT);
        ((u32*)hbuf[p])[tz] = pkh(va, vb);
      } else {
        ((u32*)hbuf[p])[tz] = 0u;
      }
      if (lane == 0)
        __hip_atomic_fetch_add(&ctr_gh, 1, __ATOMIC_RELEASE, __HIP_MEMORY_SCOPE_WORKGROUP);
      while (__hip_atomic_load(&ctr_gh, __ATOMIC_ACQUIRE, __HIP_MEMORY_SCOPE_WORKGROUP) <
             8 * (t + 1)) { }
    }

    // dot products: 4 rows x 1024 k split over 32 lanes (32 k each)
    const __half* ib = is_gi ? xbuf[p] : hbuf[p];
    const uint4* cp = (const uint4*)(ib + kc * 32);
    float a0 = 0.f, a1 = 0.f, a2 = 0.f, a3 = 0.f;
#pragma unroll
    for (int i = 0; i < 4; ++i) {
      uint4 c = cp[i];
      a0 = fdot2f(wreg[0][4 * i + 0], c.x, a0);
      a1 = fdot2f(wreg[1][4 * i + 0], c.x, a1);
      a2 = fdot2f(wreg[2][4 * i + 0], c.x, a2);
      a3 = fdot2f(wreg[3][4 * i + 0], c.x, a3);
      a0 = fdot2f(wreg[0][4 * i + 1], c.y, a0);
      a1 = fdot2f(wreg[1][4 * i + 1], c.y, a1);
      a2 = fdot2f(wreg[2][4 * i + 1], c.y, a2);
      a3 = fdot2f(wreg[3][4 * i + 1], c.y, a3);
      a0 = fdot2f(wreg[0][4 * i + 2], c.z, a0);
      a1 = fdot2f(wreg[1][4 * i + 2], c.z, a1);
      a2 = fdot2f(wreg[2][4 * i + 2], c.z, a2);
      a3 = fdot2f(wreg[3][4 * i + 2], c.z, a3);
      a0 = fdot2f(wreg[0][4 * i + 3], c.w, a0);
      a1 = fdot2f(wreg[1][4 * i + 3], c.w, a1);
      a2 = fdot2f(wreg[2][4 * i + 3], c.w, a2);
      a3 = fdot2f(wreg[3][4 * i + 3], c.w, a3);
    }
    a0 = dpp_red32(a0);
    a1 = dpp_red32(a1);
    a2 = dpp_red32(a2);
    a3 = dpp_red32(a3);
    if ((lane & 31) == 31) {
      const int base = (is_gi ? 0 : 64) + 4 * rg;
      float4 s4;
      s4.x = a0; s4.y = a1; s4.z = a2; s4.w = a3;
      *((float4*)&scr[p][base]) = s4;
    }
    __syncthreads();

    // gates (wave 0) and publish h
    if (wv == 0 && lane < h_cnt) {
      const int jj = lane;
      float ir = scr[p][3 * jj + 0] + b6[0];
      float iz = scr[p][3 * jj + 1] + b6[1];
      float in_ = scr[p][3 * jj + 2] + b6[2];
      float hr = scr[p][64 + 3 * jj + 0] + b6[3];
      float hz = scr[p][64 + 3 * jj + 1] + b6[4];
      float hn = scr[p][64 + 3 * jj + 2] + b6[5];
      float rr = 1.f / (1.f + __expf(-(ir + hr)));
      float zz = 1.f / (1.f + __expf(-(iz + hz)));
      float targ = in_ + rr * hn;
      targ = fminf(fmaxf(targ, -15.f), 15.f);
      float e2 = __expf(2.f * targ);
      float nn = (e2 - 1.f) / (e2 + 1.f);
      float hp = __half2float(hbuf[p][h_base + jj]);
      float hv = (1.f - zz) * nn + zz * hp;
      __hip_atomic_store(&Xout[(size_t)t * HID + h_base + jj], hv,
                         __ATOMIC_RELAXED, __HIP_MEMORY_SCOPE_AGENT);
    }
    if (tid == 0)
      __hip_atomic_fetch_add(&f_out[t], 1, __ATOMIC_RELEASE, __HIP_MEMORY_SCOPE_AGENT);
  }
}

// ---------------------------------------------------------------------------
// lin2: out[o,t,io] = h5[t] . w2[o*32+io] + b2
// ---------------------------------------------------------------------------
__global__ __launch_bounds__(256) void lin2_kernel(
    const float* __restrict__ h5, const float* __restrict__ w2,
    const float* __restrict__ b2, float* __restrict__ out) {
  __shared__ float at[64][65];
  __shared__ float bt[64][65];
  const int tid = threadIdx.x;
  const int t0 = blockIdx.x * 64;
  const int j0 = blockIdx.y * 64;
  const int tt0 = (tid & 15) * 4;
  const int jj0 = (tid >> 4) * 4;
  float acc[4][4] = {};
  for (int kc = 0; kc < 1024; kc += 64) {
    __syncthreads();
#pragma unroll
    for (int m = 0; m < 16; ++m) {
      int e = tid + m * 256;
      int tt = e >> 6, kk = e & 63;
      at[tt][kk] = h5[(size_t)(t0 + tt) * HID + kc + kk];
    }
#pragma unroll
    for (int m = 0; m < 16; ++m) {
      int e = tid + m * 256;
      int jj = e >> 6, kk = e & 63;
      bt[jj][kk] = w2[(size_t)(j0 + jj) * HID + kc + kk];
    }
    __syncthreads();
    for (int kk = 0; kk < 64; ++kk) {
      float la[4], wa[4];
#pragma unroll
      for (int i = 0; i < 4; ++i) la[i] = at[tt0 + i][kk];
#pragma unroll
      for (int j = 0; j < 4; ++j) wa[j] = bt[jj0 + j][kk];
#pragma unroll
      for (int i = 0; i < 4; ++i)
#pragma unroll
        for (int j = 0; j < 4; ++j) acc[i][j] = fmaf(la[i], wa[j], acc[i][j]);
    }
  }
#pragma unroll
  for (int i = 0; i < 4; ++i)
#pragma unroll
    for (int jq = 0; jq < 4; ++jq) {
      int j = j0 + jj0 + jq;
      out[(size_t)(j >> 5) * (TSTEPS * 32) + (size_t)(t0 + tt0 + i) * 32 + (j & 31)] =
          acc[i][jq] + b2[j];
    }
}

extern "C" void kernel_launch(void* const* d_in, const int* in_sizes, int n_in,
                              void* d_out, int out_size, void* d_ws, size_t ws_size,
                              hipStream_t stream) {
  const float* x   = (const float*)d_in[0];
  const float* w1  = (const float*)d_in[1];
  const float* b1  = (const float*)d_in[2];
  const float* wih = (const float*)d_in[3];
  const float* whh = (const float*)d_in[4];
  const float* bih = (const float*)d_in[5];
  const float* bhh = (const float*)d_in[6];
  const float* w2  = (const float*)d_in[7];
  const float* b2  = (const float*)d_in[8];
  float* out = (float*)d_out;

  int* flags = (int*)d_ws;
  float* X   = (float*)((char*)d_ws + 65536);  // 6 slabs of [T][H] fp32

  hipMemsetAsync(d_ws, 0, (NDEPTH + 1) * TSTEPS * sizeof(int), stream);
  lin1_kernel<<<dim3(64, 8), 256, 0, stream>>>(x, w1, b1, X);
  gru_pipe<<<NBLOCKS, 1024, 0, stream>>>(wih, whh, bih, bhh, X, flags);
  lin2_kernel<<<dim3(32, 4), 256, 0, stream>>>(X + (size_t)NDEPTH * TSTEPS * HID,
                                               w2, b2, out);
}

// Round 2
// 12178.226 us; speedup vs baseline: 10.7022x; 10.7022x over previous
//
#include <hip/hip_runtime.h>
#include <hip/hip_fp16.h>

typedef unsigned int u32;
typedef unsigned long long u64;

#define TSTEPS 2048
#define HID    1024
#define NDEPTH 5
#define GSTAGE 51
#define NBLOCKS (NDEPTH * GSTAGE)   // 255 blocks, <=1 per CU

typedef _Float16 f16x2v __attribute__((ext_vector_type(2)));

#if defined(__has_builtin)
# if __has_builtin(__builtin_amdgcn_fdot2)
#  define HAVE_FDOT2 1
# endif
#endif

__device__ __forceinline__ float fdot2f(u32 a, u32 b, float c) {
  f16x2v x, y;
  __builtin_memcpy(&x, &a, 4);
  __builtin_memcpy(&y, &b, 4);
#ifdef HAVE_FDOT2
  return __builtin_amdgcn_fdot2(x, y, c, false);
#else
  return c + (float)x[0] * (float)y[0] + (float)x[1] * (float)y[1];
#endif
}

__device__ __forceinline__ u32 pkh(float a, float b) {
  __half2 h = __floats2half2_rn(a, b);
  u32 r;
  __builtin_memcpy(&r, &h, 4);
  return r;
}

// sum within each 32-lane half; valid in lanes 31 and 63
__device__ __forceinline__ float dpp_red32(float v) {
  int t, vi;
  __builtin_memcpy(&vi, &v, 4);
  float tf;
#define STEP(CTRL)                                                        \
  t = __builtin_amdgcn_update_dpp(0, vi, CTRL, 0xF, 0xF, true);           \
  __builtin_memcpy(&tf, &t, 4);                                           \
  v += tf;                                                                \
  __builtin_memcpy(&vi, &v, 4);
  STEP(0x111) // row_shr:1
  STEP(0x112) // row_shr:2
  STEP(0x114) // row_shr:4
  STEP(0x118) // row_shr:8
  STEP(0x142) // row_bcast:15
#undef STEP
  return v;
}

// one wave: each lane watches one per-block flag word (write-once, relaxed)
__device__ __forceinline__ void poll_group(const int* g) {
  const int lane = threadIdx.x & 63;
  const int idx = (lane < GSTAGE) ? lane : (GSTAGE - 1);
  const int* p = g + idx;
  while (__hip_atomic_load(p, __ATOMIC_RELAXED, __HIP_MEMORY_SCOPE_AGENT) == 0) {
  }
}

// ---------------------------------------------------------------------------
// lin1: pre[t][h] = lines[t] . w1[h] + b1[h]
// ---------------------------------------------------------------------------
__global__ __launch_bounds__(256) void lin1_kernel(
    const float* __restrict__ x, const float* __restrict__ w1,
    const float* __restrict__ b1, float* __restrict__ X0) {
  __shared__ float lt[32][65];
  __shared__ float wt[128][65];
  const int tid = threadIdx.x;
  const int t0 = blockIdx.x * 32;
  const int h0 = blockIdx.y * 128;
  const int tt0 = (tid & 7) * 4;
  const int hh0 = (tid >> 3) * 4;
  float acc[4][4] = {};
  for (int kc = 0; kc < 512; kc += 64) {
    __syncthreads();
#pragma unroll
    for (int m = 0; m < 8; ++m) {
      int e = tid + m * 256;
      int tt = e >> 6, kk = e & 63;
      int k = kc + kk;
      int a = k >> 5, io = k & 31;
      int d = (a == 0) ? 0 : (a + 1);
      int st = t0 + tt - d;
      lt[tt][kk] = (st >= 0) ? x[st * 32 + io] : 0.f;
    }
#pragma unroll
    for (int m = 0; m < 32; ++m) {
      int e = tid + m * 256;
      int hh = e >> 6, kk = e & 63;
      wt[hh][kk] = w1[(size_t)(h0 + hh) * 512 + kc + kk];
    }
    __syncthreads();
    for (int kk = 0; kk < 64; ++kk) {
      float la[4], wa[4];
#pragma unroll
      for (int i = 0; i < 4; ++i) la[i] = lt[tt0 + i][kk];
#pragma unroll
      for (int j = 0; j < 4; ++j) wa[j] = wt[hh0 + j][kk];
#pragma unroll
      for (int i = 0; i < 4; ++i)
#pragma unroll
        for (int j = 0; j < 4; ++j) acc[i][j] = fmaf(la[i], wa[j], acc[i][j]);
    }
  }
#pragma unroll
  for (int i = 0; i < 4; ++i)
#pragma unroll
    for (int j = 0; j < 4; ++j)
      X0[(size_t)(t0 + tt0 + i) * HID + h0 + hh0 + j] =
          acc[i][j] + b1[h0 + hh0 + j];
}

// ---------------------------------------------------------------------------
// persistent pipelined GRU: 5 stages x 51 blocks, fp16 weights in VGPRs
// 512 threads (8 waves, 2/SIMD -> 256-VGPR budget, no AGPR/scratch traffic)
// ---------------------------------------------------------------------------
__global__ __launch_bounds__(512, 2) void gru_pipe(
    const float* __restrict__ wih, const float* __restrict__ whh,
    const float* __restrict__ bih, const float* __restrict__ bhh,
    float* __restrict__ X, int* __restrict__ flags) {
  const int bid = blockIdx.x;
  const int l   = bid / GSTAGE;
  const int bs  = bid % GSTAGE;
  const int tid = (int)threadIdx.x;
  const int lane = tid & 63;
  const int wv   = tid >> 6;           // 0..7
  const int half = lane >> 5;
  const int kc   = lane & 31;
  const bool is_gi = (wv < 4);
  const int rg = (wv & 3) * 2 + half;  // 0..7 row-group within gi or gh set

  const int h_base = (bs * HID) / GSTAGE;
  const int h_cnt  = ((bs + 1) * HID) / GSTAGE - h_base;   // 20 or 21
  const int ndot = 3 * h_cnt;                              // <= 63

  const float* mat = (is_gi ? wih : whh) + (size_t)l * 3 * HID * HID;

  // 8 rows x 32 k-values (fp16, packed 2/reg) = 128 VGPRs of weights.
  // lane kc owns k = kc*8 + s*256 + j  (s=0..3, j=0..7)  -> coalesced LDS reads
  u32 wreg[8][16];
#pragma unroll
  for (int r = 0; r < 8; ++r) {
    const int d = 8 * rg + r;
    if (d < ndot) {
      const int jj = d / 3, g = d % 3;
      const float* rowp = mat + (size_t)(g * HID + h_base + jj) * HID;
#pragma unroll
      for (int s = 0; s < 4; ++s) {
        const float4* sp = (const float4*)(rowp + kc * 8 + s * 256);
        float4 f0 = sp[0], f1 = sp[1];
        wreg[r][s * 4 + 0] = pkh(f0.x, f0.y);
        wreg[r][s * 4 + 1] = pkh(f0.z, f0.w);
        wreg[r][s * 4 + 2] = pkh(f1.x, f1.y);
        wreg[r][s * 4 + 3] = pkh(f1.z, f1.w);
      }
    } else {
#pragma unroll
      for (int i = 0; i < 16; ++i) wreg[r][i] = 0u;
    }
  }

  float b6[6] = {0.f, 0.f, 0.f, 0.f, 0.f, 0.f};
  if (wv == 0 && lane < h_cnt) {
#pragma unroll
    for (int g = 0; g < 3; ++g) {
      b6[g]     = bih[(size_t)l * 3 * HID + g * HID + h_base + lane];
      b6[3 + g] = bhh[(size_t)l * 3 * HID + g * HID + h_base + lane];
    }
  }

  __shared__ __align__(16) __half xbuf[HID];
  __shared__ __align__(16) __half hbuf[HID];
  __shared__ __align__(16) float scr[128];

  const float* Xin = X + (size_t)l * TSTEPS * HID;
  float* Xout      = X + (size_t)(l + 1) * TSTEPS * HID;

  for (int t = 0; t < TSTEPS; ++t) {
    // ---- wait for inputs: wave 3 polls x_t (layer l-1), wave 7 polls h_{t-1}
    if (wv == 3 && l > 0) poll_group(flags + (((size_t)(l - 1) * TSTEPS + t) << 6));
    if (wv == 7 && t > 0) poll_group(flags + (((size_t)l * TSTEPS + (t - 1)) << 6));
    asm volatile("" ::: "memory");
    __syncthreads();

    // ---- stage inputs -> fp16 LDS (relaxed agent loads: LLC-direct, fresh)
    if (is_gi) {
      const int gt = tid;  // 0..255, 4 floats each
      const u64* src = (const u64*)(Xin + (size_t)t * HID) + 2 * gt;
      u64 v0 = __hip_atomic_load(src, __ATOMIC_RELAXED, __HIP_MEMORY_SCOPE_AGENT);
      u64 v1 = __hip_atomic_load(src + 1, __ATOMIC_RELAXED, __HIP_MEMORY_SCOPE_AGENT);
      float2 f0, f1;
      __builtin_memcpy(&f0, &v0, 8);
      __builtin_memcpy(&f1, &v1, 8);
      uint2 w;
      w.x = pkh(f0.x, f0.y);
      w.y = pkh(f1.x, f1.y);
      ((uint2*)xbuf)[gt] = w;
    } else {
      const int gt = tid - 256;
      if (t > 0) {
        const u64* src = (const u64*)(Xout + (size_t)(t - 1) * HID) + 2 * gt;
        u64 v0 = __hip_atomic_load(src, __ATOMIC_RELAXED, __HIP_MEMORY_SCOPE_AGENT);
        u64 v1 = __hip_atomic_load(src + 1, __ATOMIC_RELAXED, __HIP_MEMORY_SCOPE_AGENT);
        float2 f0, f1;
        __builtin_memcpy(&f0, &v0, 8);
        __builtin_memcpy(&f1, &v1, 8);
        uint2 w;
        w.x = pkh(f0.x, f0.y);
        w.y = pkh(f1.x, f1.y);
        ((uint2*)hbuf)[gt] = w;
      } else {
        uint2 z; z.x = 0u; z.y = 0u;
        ((uint2*)hbuf)[gt] = z;
      }
    }
    __syncthreads();

    // ---- dots: 8 rows/thread, conflict-free coalesced LDS reads
    const __half* ib = is_gi ? xbuf : hbuf;
    const uint4* cp = (const uint4*)ib;
    float a[8] = {0.f, 0.f, 0.f, 0.f, 0.f, 0.f, 0.f, 0.f};
#pragma unroll
    for (int s = 0; s < 4; ++s) {
      uint4 c = cp[kc + 32 * s];
#pragma unroll
      for (int r = 0; r < 8; ++r) {
        a[r] = fdot2f(wreg[r][4 * s + 0], c.x, a[r]);
        a[r] = fdot2f(wreg[r][4 * s + 1], c.y, a[r]);
        a[r] = fdot2f(wreg[r][4 * s + 2], c.z, a[r]);
        a[r] = fdot2f(wreg[r][4 * s + 3], c.w, a[r]);
      }
    }
#pragma unroll
    for (int r = 0; r < 8; ++r) a[r] = dpp_red32(a[r]);
    if ((lane & 31) == 31) {
      const int base = (is_gi ? 0 : 64) + 8 * rg;
      float4 s0, s1;
      s0.x = a[0]; s0.y = a[1]; s0.z = a[2]; s0.w = a[3];
      s1.x = a[4]; s1.y = a[5]; s1.z = a[6]; s1.w = a[7];
      ((float4*)&scr[base])[0] = s0;
      ((float4*)&scr[base])[1] = s1;
    }
    __syncthreads();

    // ---- gates (wave 0), publish h slice, release per-block flag
    if (wv == 0) {
      if (lane < h_cnt) {
        const int jj = lane;
        float ir = scr[3 * jj + 0] + b6[0];
        float iz = scr[3 * jj + 1] + b6[1];
        float in_ = scr[3 * jj + 2] + b6[2];
        float hr = scr[64 + 3 * jj + 0] + b6[3];
        float hz = scr[64 + 3 * jj + 1] + b6[4];
        float hn = scr[64 + 3 * jj + 2] + b6[5];
        float rr = 1.f / (1.f + __expf(-(ir + hr)));
        float zz = 1.f / (1.f + __expf(-(iz + hz)));
        float targ = in_ + rr * hn;
        targ = fminf(fmaxf(targ, -15.f), 15.f);
        float e2 = __expf(2.f * targ);
        float nn = (e2 - 1.f) / (e2 + 1.f);
        float hp = __half2float(hbuf[h_base + jj]);
        float hv = (1.f - zz) * nn + zz * hp;
        __hip_atomic_store(&Xout[(size_t)t * HID + h_base + jj], hv,
                           __ATOMIC_RELAXED, __HIP_MEMORY_SCOPE_AGENT);
      }
      if (lane == 0) {
        __hip_atomic_store(flags + ((((size_t)l * TSTEPS + t) << 6) + bs), 1,
                           __ATOMIC_RELEASE, __HIP_MEMORY_SCOPE_AGENT);
      }
    }
  }
}

// ---------------------------------------------------------------------------
// lin2: out[o,t,io] = h5[t] . w2[o*32+io] + b2
// ---------------------------------------------------------------------------
__global__ __launch_bounds__(256) void lin2_kernel(
    const float* __restrict__ h5, const float* __restrict__ w2,
    const float* __restrict__ b2, float* __restrict__ out) {
  __shared__ float at[64][65];
  __shared__ float bt[64][65];
  const int tid = threadIdx.x;
  const int t0 = blockIdx.x * 64;
  const int j0 = blockIdx.y * 64;
  const int tt0 = (tid & 15) * 4;
  const int jj0 = (tid >> 4) * 4;
  float acc[4][4] = {};
  for (int kc = 0; kc < 1024; kc += 64) {
    __syncthreads();
#pragma unroll
    for (int m = 0; m < 16; ++m) {
      int e = tid + m * 256;
      int tt = e >> 6, kk = e & 63;
      at[tt][kk] = h5[(size_t)(t0 + tt) * HID + kc + kk];
    }
#pragma unroll
    for (int m = 0; m < 16; ++m) {
      int e = tid + m * 256;
      int jj = e >> 6, kk = e & 63;
      bt[jj][kk] = w2[(size_t)(j0 + jj) * HID + kc + kk];
    }
    __syncthreads();
    for (int kk = 0; kk < 64; ++kk) {
      float la[4], wa[4];
#pragma unroll
      for (int i = 0; i < 4; ++i) la[i] = at[tt0 + i][kk];
#pragma unroll
      for (int j = 0; j < 4; ++j) wa[j] = bt[jj0 + j][kk];
#pragma unroll
      for (int i = 0; i < 4; ++i)
#pragma unroll
        for (int j = 0; j < 4; ++j) acc[i][j] = fmaf(la[i], wa[j], acc[i][j]);
    }
  }
#pragma unroll
  for (int i = 0; i < 4; ++i)
#pragma unroll
    for (int jq = 0; jq < 4; ++jq) {
      int j = j0 + jj0 + jq;
      out[(size_t)(j >> 5) * (TSTEPS * 32) + (size_t)(t0 + tt0 + i) * 32 + (j & 31)] =
          acc[i][jq] + b2[j];
    }
}

extern "C" void kernel_launch(void* const* d_in, const int* in_sizes, int n_in,
                              void* d_out, int out_size, void* d_ws, size_t ws_size,
                              hipStream_t stream) {
  const float* x   = (const float*)d_in[0];
  const float* w1  = (const float*)d_in[1];
  const float* b1  = (const float*)d_in[2];
  const float* wih = (const float*)d_in[3];
  const float* whh = (const float*)d_in[4];
  const float* bih = (const float*)d_in[5];
  const float* bhh = (const float*)d_in[6];
  const float* w2  = (const float*)d_in[7];
  const float* b2  = (const float*)d_in[8];
  float* out = (float*)d_out;

  // ws layout: flags (5*2048*64 ints, 2.62 MB, 4 MB reserved) | X slabs (6*T*H fp32)
  int* flags = (int*)d_ws;
  float* X   = (float*)((char*)d_ws + (4u << 20));

  hipMemsetAsync(d_ws, 0, (size_t)NDEPTH * TSTEPS * 64 * sizeof(int), stream);
  lin1_kernel<<<dim3(64, 8), 256, 0, stream>>>(x, w1, b1, X);
  gru_pipe<<<NBLOCKS, 512, 0, stream>>>(wih, whh, bih, bhh, X, flags);
  lin2_kernel<<<dim3(32, 4), 256, 0, stream>>>(X + (size_t)NDEPTH * TSTEPS * HID,
                                               w2, b2, out);
}

// Round 3
// 5014.685 us; speedup vs baseline: 25.9903x; 2.4285x over previous
//
#include <hip/hip_runtime.h>
#include <hip/hip_fp16.h>

typedef unsigned int u32;
typedef unsigned long long u64;

#define TSTEPS 2048
#define HID    1024
#define NDEPTH 5
#define GSTAGE 51
#define NBLOCKS (NDEPTH * GSTAGE)   // 255 blocks, <=1 per CU
#define CANARY  0x7f800000u         // +inf: unreachable by GRU outputs (|h|<=1) or lin1 output

typedef _Float16 f16x2v __attribute__((ext_vector_type(2)));

#if defined(__has_builtin)
# if __has_builtin(__builtin_amdgcn_fdot2)
#  define HAVE_FDOT2 1
# endif
#endif

__device__ __forceinline__ float fdot2f(u32 a, u32 b, float c) {
  f16x2v x, y;
  __builtin_memcpy(&x, &a, 4);
  __builtin_memcpy(&y, &b, 4);
#ifdef HAVE_FDOT2
  return __builtin_amdgcn_fdot2(x, y, c, false);
#else
  return c + (float)x[0] * (float)y[0] + (float)x[1] * (float)y[1];
#endif
}

__device__ __forceinline__ u32 pkh(float a, float b) {
  __half2 h = __floats2half2_rn(a, b);
  u32 r;
  __builtin_memcpy(&r, &h, 4);
  return r;
}

__device__ __forceinline__ float u2f(u32 u) {
  float f;
  __builtin_memcpy(&f, &u, 4);
  return f;
}

// sum within each 32-lane half; valid in lanes 31 and 63
__device__ __forceinline__ float dpp_red32(float v) {
  int t, vi;
  __builtin_memcpy(&vi, &v, 4);
  float tf;
#define STEP(CTRL)                                                        \
  t = __builtin_amdgcn_update_dpp(0, vi, CTRL, 0xF, 0xF, true);           \
  __builtin_memcpy(&tf, &t, 4);                                           \
  v += tf;                                                                \
  __builtin_memcpy(&vi, &v, 4);
  STEP(0x111) // row_shr:1
  STEP(0x112) // row_shr:2
  STEP(0x114) // row_shr:4
  STEP(0x118) // row_shr:8
  STEP(0x142) // row_bcast:15
#undef STEP
  return v;
}

// LLC-direct 16B load; spin until no dword equals the canary. The poll IS the
// data load: one fabric RTT delivers both validity and payload.
__device__ __forceinline__ uint4 spin_load16(const void* p) {
  uint4 v;
  do {
    asm volatile("global_load_dwordx4 %0, %1, off sc0 sc1\n\ts_waitcnt vmcnt(0)"
                 : "=v"(v)
                 : "v"(p));
  } while (v.x == CANARY || v.y == CANARY || v.z == CANARY || v.w == CANARY);
  return v;
}

__device__ __forceinline__ void store_sc(float* p, float v) {
  asm volatile("global_store_dword %0, %1, off sc0 sc1" :: "v"(p), "v"(v));
}

// ---------------------------------------------------------------------------
// canary fill for X slabs 1..5 (write-once dataflow cells)
// ---------------------------------------------------------------------------
__global__ __launch_bounds__(256) void fill_canary(u32* __restrict__ p, long n) {
  long i = ((long)blockIdx.x * 256 + threadIdx.x) * 4;
  const long stride = (long)gridDim.x * 256 * 4;
  uint4 c;
  c.x = CANARY; c.y = CANARY; c.z = CANARY; c.w = CANARY;
  for (; i < n; i += stride) *(uint4*)(p + i) = c;
}

// ---------------------------------------------------------------------------
// lin1: pre[t][h] = lines[t] . w1[h] + b1[h]
// ---------------------------------------------------------------------------
__global__ __launch_bounds__(256) void lin1_kernel(
    const float* __restrict__ x, const float* __restrict__ w1,
    const float* __restrict__ b1, float* __restrict__ X0) {
  __shared__ float lt[32][65];
  __shared__ float wt[128][65];
  const int tid = threadIdx.x;
  const int t0 = blockIdx.x * 32;
  const int h0 = blockIdx.y * 128;
  const int tt0 = (tid & 7) * 4;
  const int hh0 = (tid >> 3) * 4;
  float acc[4][4] = {};
  for (int kc = 0; kc < 512; kc += 64) {
    __syncthreads();
#pragma unroll
    for (int m = 0; m < 8; ++m) {
      int e = tid + m * 256;
      int tt = e >> 6, kk = e & 63;
      int k = kc + kk;
      int a = k >> 5, io = k & 31;
      int d = (a == 0) ? 0 : (a + 1);
      int st = t0 + tt - d;
      lt[tt][kk] = (st >= 0) ? x[st * 32 + io] : 0.f;
    }
#pragma unroll
    for (int m = 0; m < 32; ++m) {
      int e = tid + m * 256;
      int hh = e >> 6, kk = e & 63;
      wt[hh][kk] = w1[(size_t)(h0 + hh) * 512 + kc + kk];
    }
    __syncthreads();
    for (int kk = 0; kk < 64; ++kk) {
      float la[4], wa[4];
#pragma unroll
      for (int i = 0; i < 4; ++i) la[i] = lt[tt0 + i][kk];
#pragma unroll
      for (int j = 0; j < 4; ++j) wa[j] = wt[hh0 + j][kk];
#pragma unroll
      for (int i = 0; i < 4; ++i)
#pragma unroll
        for (int j = 0; j < 4; ++j) acc[i][j] = fmaf(la[i], wa[j], acc[i][j]);
    }
  }
#pragma unroll
  for (int i = 0; i < 4; ++i)
#pragma unroll
    for (int j = 0; j < 4; ++j)
      X0[(size_t)(t0 + tt0 + i) * HID + h0 + hh0 + j] =
          acc[i][j] + b1[h0 + hh0 + j];
}

// ---------------------------------------------------------------------------
// persistent pipelined GRU: 5 stages x 51 blocks; fp16 weights register-resident
// flagless dataflow: payload-carried validity (canary), LLC-direct loads/stores
// ---------------------------------------------------------------------------
__global__ __launch_bounds__(512, 2) void gru_pipe(
    const float* __restrict__ wih, const float* __restrict__ whh,
    const float* __restrict__ bih, const float* __restrict__ bhh,
    float* __restrict__ X) {
  const int bid = blockIdx.x;
  const int l   = bid / GSTAGE;
  const int bs  = bid % GSTAGE;
  const int tid = (int)threadIdx.x;
  const int lane = tid & 63;
  const int wv   = tid >> 6;           // 0..7
  const int half = lane >> 5;
  const int kc   = lane & 31;
  const bool is_gi = (wv < 4);
  const int rg = (wv & 3) * 2 + half;  // 0..7 row-group within gi or gh set

  const int h_base = (bs * HID) / GSTAGE;
  const int h_cnt  = ((bs + 1) * HID) / GSTAGE - h_base;   // 20 or 21
  const int ndot = 3 * h_cnt;                              // <= 63

  const float* mat = (is_gi ? wih : whh) + (size_t)l * 3 * HID * HID;

  // 8 rows x 32 k-values (fp16, packed 2/reg) = 128 regs of weights.
  // lane kc owns k = kc*8 + s*256 + j  (s=0..3, j=0..7)
  u32 wreg[8][16];
#pragma unroll
  for (int r = 0; r < 8; ++r) {
    const int d = 8 * rg + r;
    if (d < ndot) {
      const int jj = d / 3, g = d % 3;
      const float* rowp = mat + (size_t)(g * HID + h_base + jj) * HID;
#pragma unroll
      for (int s = 0; s < 4; ++s) {
        const float4* sp = (const float4*)(rowp + kc * 8 + s * 256);
        float4 f0 = sp[0], f1 = sp[1];
        wreg[r][s * 4 + 0] = pkh(f0.x, f0.y);
        wreg[r][s * 4 + 1] = pkh(f0.z, f0.w);
        wreg[r][s * 4 + 2] = pkh(f1.x, f1.y);
        wreg[r][s * 4 + 3] = pkh(f1.z, f1.w);
      }
    } else {
#pragma unroll
      for (int i = 0; i < 16; ++i) wreg[r][i] = 0u;
    }
  }

  float b6[6] = {0.f, 0.f, 0.f, 0.f, 0.f, 0.f};
  if (wv == 0 && lane < h_cnt) {
#pragma unroll
    for (int g = 0; g < 3; ++g) {
      b6[g]     = bih[(size_t)l * 3 * HID + g * HID + h_base + lane];
      b6[3 + g] = bhh[(size_t)l * 3 * HID + g * HID + h_base + lane];
    }
  }

  __shared__ __align__(16) __half xbuf[2][HID];
  __shared__ __align__(16) __half hbuf[2][HID];
  __shared__ __align__(16) float scr[2][128];

  const float* Xin = X + (size_t)l * TSTEPS * HID;
  float* Xout      = X + (size_t)(l + 1) * TSTEPS * HID;

  for (int t = 0; t < TSTEPS; ++t) {
    const int p = t & 1;

    // ---- stage inputs -> fp16 LDS; the spin-load IS the synchronization
    if (is_gi) {
      const int gt = tid;  // 0..255, 4 floats each
      uint4 v = spin_load16((const char*)(Xin + (size_t)t * HID) + 16 * gt);
      uint2 w;
      w.x = pkh(u2f(v.x), u2f(v.y));
      w.y = pkh(u2f(v.z), u2f(v.w));
      ((uint2*)xbuf[p])[gt] = w;
    } else {
      const int gt = tid - 256;
      if (t > 0) {
        uint4 v = spin_load16((const char*)(Xout + (size_t)(t - 1) * HID) + 16 * gt);
        uint2 w;
        w.x = pkh(u2f(v.x), u2f(v.y));
        w.y = pkh(u2f(v.z), u2f(v.w));
        ((uint2*)hbuf[p])[gt] = w;
      } else {
        uint2 z; z.x = 0u; z.y = 0u;
        ((uint2*)hbuf[p])[gt] = z;
      }
    }
    __syncthreads();

    // ---- dots: 8 rows/thread, conflict-free LDS reads
    const __half* ib = is_gi ? xbuf[p] : hbuf[p];
    const uint4* cp = (const uint4*)ib;
    float a[8] = {0.f, 0.f, 0.f, 0.f, 0.f, 0.f, 0.f, 0.f};
#pragma unroll
    for (int s = 0; s < 4; ++s) {
      uint4 c = cp[kc + 32 * s];
#pragma unroll
      for (int r = 0; r < 8; ++r) {
        a[r] = fdot2f(wreg[r][4 * s + 0], c.x, a[r]);
        a[r] = fdot2f(wreg[r][4 * s + 1], c.y, a[r]);
        a[r] = fdot2f(wreg[r][4 * s + 2], c.z, a[r]);
        a[r] = fdot2f(wreg[r][4 * s + 3], c.w, a[r]);
      }
    }
#pragma unroll
    for (int r = 0; r < 8; ++r) a[r] = dpp_red32(a[r]);
    if ((lane & 31) == 31) {
      const int base = (is_gi ? 0 : 64) + 8 * rg;
      float4 s0, s1;
      s0.x = a[0]; s0.y = a[1]; s0.z = a[2]; s0.w = a[3];
      s1.x = a[4]; s1.y = a[5]; s1.z = a[6]; s1.w = a[7];
      ((float4*)&scr[p][base])[0] = s0;
      ((float4*)&scr[p][base])[1] = s1;
    }
    __syncthreads();

    // ---- gates (wave 0): compute h_t slice, publish LLC-direct, no fences
    if (wv == 0 && lane < h_cnt) {
      const int jj = lane;
      float ir = scr[p][3 * jj + 0] + b6[0];
      float iz = scr[p][3 * jj + 1] + b6[1];
      float in_ = scr[p][3 * jj + 2] + b6[2];
      float hr = scr[p][64 + 3 * jj + 0] + b6[3];
      float hz = scr[p][64 + 3 * jj + 1] + b6[4];
      float hn = scr[p][64 + 3 * jj + 2] + b6[5];
      float rr = 1.f / (1.f + __expf(-(ir + hr)));
      float zz = 1.f / (1.f + __expf(-(iz + hz)));
      float targ = in_ + rr * hn;
      targ = fminf(fmaxf(targ, -15.f), 15.f);
      float e2 = __expf(2.f * targ);
      float nn = (e2 - 1.f) / (e2 + 1.f);
      float hp = __half2float(hbuf[p][h_base + jj]);
      float hv = (1.f - zz) * nn + zz * hp;
      store_sc(&Xout[(size_t)t * HID + h_base + jj], hv);
    }
    // no third barrier: buffers are double-buffered; buf[p^1] was last touched
    // at iteration t-1 and is protected by this iteration's two barriers.
  }
}

// ---------------------------------------------------------------------------
// lin2: out[o,t,io] = h5[t] . w2[o*32+io] + b2
// ---------------------------------------------------------------------------
__global__ __launch_bounds__(256) void lin2_kernel(
    const float* __restrict__ h5, const float* __restrict__ w2,
    const float* __restrict__ b2, float* __restrict__ out) {
  __shared__ float at[64][65];
  __shared__ float bt[64][65];
  const int tid = threadIdx.x;
  const int t0 = blockIdx.x * 64;
  const int j0 = blockIdx.y * 64;
  const int tt0 = (tid & 15) * 4;
  const int jj0 = (tid >> 4) * 4;
  float acc[4][4] = {};
  for (int kc = 0; kc < 1024; kc += 64) {
    __syncthreads();
#pragma unroll
    for (int m = 0; m < 16; ++m) {
      int e = tid + m * 256;
      int tt = e >> 6, kk = e & 63;
      at[tt][kk] = h5[(size_t)(t0 + tt) * HID + kc + kk];
    }
#pragma unroll
    for (int m = 0; m < 16; ++m) {
      int e = tid + m * 256;
      int jj = e >> 6, kk = e & 63;
      bt[jj][kk] = w2[(size_t)(j0 + jj) * HID + kc + kk];
    }
    __syncthreads();
    for (int kk = 0; kk < 64; ++kk) {
      float la[4], wa[4];
#pragma unroll
      for (int i = 0; i < 4; ++i) la[i] = at[tt0 + i][kk];
#pragma unroll
      for (int j = 0; j < 4; ++j) wa[j] = bt[jj0 + j][kk];
#pragma unroll
      for (int i = 0; i < 4; ++i)
#pragma unroll
        for (int j = 0; j < 4; ++j) acc[i][j] = fmaf(la[i], wa[j], acc[i][j]);
    }
  }
#pragma unroll
  for (int i = 0; i < 4; ++i)
#pragma unroll
    for (int jq = 0; jq < 4; ++jq) {
      int j = j0 + jj0 + jq;
      out[(size_t)(j >> 5) * (TSTEPS * 32) + (size_t)(t0 + tt0 + i) * 32 + (j & 31)] =
          acc[i][jq] + b2[j];
    }
}

extern "C" void kernel_launch(void* const* d_in, const int* in_sizes, int n_in,
                              void* d_out, int out_size, void* d_ws, size_t ws_size,
                              hipStream_t stream) {
  const float* x   = (const float*)d_in[0];
  const float* w1  = (const float*)d_in[1];
  const float* b1  = (const float*)d_in[2];
  const float* wih = (const float*)d_in[3];
  const float* whh = (const float*)d_in[4];
  const float* bih = (const float*)d_in[5];
  const float* bhh = (const float*)d_in[6];
  const float* w2  = (const float*)d_in[7];
  const float* b2  = (const float*)d_in[8];
  float* out = (float*)d_out;

  float* X = (float*)d_ws;  // 6 slabs of [T][H] fp32 (50.3 MB)

  // canary-fill slabs 1..5 (write-once cells; re-armed every launch/replay)
  fill_canary<<<1280, 256, 0, stream>>>((u32*)(X + (size_t)TSTEPS * HID),
                                        (long)NDEPTH * TSTEPS * HID);
  lin1_kernel<<<dim3(64, 8), 256, 0, stream>>>(x, w1, b1, X);
  gru_pipe<<<NBLOCKS, 512, 0, stream>>>(wih, whh, bih, bhh, X);
  lin2_kernel<<<dim3(32, 4), 256, 0, stream>>>(X + (size_t)NDEPTH * TSTEPS * HID,
                                               w2, b2, out);
}

// Round 4
// 3516.897 us; speedup vs baseline: 37.0592x; 1.4259x over previous
//
#include <hip/hip_runtime.h>
#include <hip/hip_fp16.h>

typedef unsigned int u32;

#define TSTEPS 2048
#define HID    1024
#define NDEPTH 5
#define GSTAGE 51
#define NBLOCKS (NDEPTH * GSTAGE)   // 255 blocks, 1 per CU
#define HCAN   0x7c00u              // fp16 +inf: unreachable (|h|<=1, lin1 out ~N(0,0.45))
#define DCAN   0x7c007c00u

typedef _Float16 f16x2v __attribute__((ext_vector_type(2)));

#if defined(__has_builtin)
# if __has_builtin(__builtin_amdgcn_fdot2)
#  define HAVE_FDOT2 1
# endif
#endif

__device__ __forceinline__ float fdot2f(u32 a, u32 b, float c) {
  f16x2v x, y;
  __builtin_memcpy(&x, &a, 4);
  __builtin_memcpy(&y, &b, 4);
#ifdef HAVE_FDOT2
  return __builtin_amdgcn_fdot2(x, y, c, false);
#else
  return c + (float)x[0] * (float)y[0] + (float)x[1] * (float)y[1];
#endif
}

__device__ __forceinline__ u32 pkh(float a, float b) {
  __half2 h = __floats2half2_rn(a, b);
  u32 r;
  __builtin_memcpy(&r, &h, 4);
  return r;
}

// sum within each 32-lane half; valid in lanes 31 and 63
__device__ __forceinline__ float dpp_red32(float v) {
  int t, vi;
  __builtin_memcpy(&vi, &v, 4);
  float tf;
#define STEP(CTRL)                                                        \
  t = __builtin_amdgcn_update_dpp(0, vi, CTRL, 0xF, 0xF, true);           \
  __builtin_memcpy(&tf, &t, 4);                                           \
  v += tf;                                                                \
  __builtin_memcpy(&vi, &v, 4);
  STEP(0x111)
  STEP(0x112)
  STEP(0x114)
  STEP(0x118)
  STEP(0x142)
#undef STEP
  return v;
}

// LLC-direct 8B spin-load; exits when no fp16 halfword is the canary.
__device__ __forceinline__ uint2 spin_load8(const void* p) {
  uint2 v;
  for (;;) {
    asm volatile("global_load_dwordx2 %0, %1, off sc0 sc1\n\ts_waitcnt vmcnt(0)"
                 : "=v"(v) : "v"(p));
    if (((v.x & 0xffffu) != HCAN) & ((v.x >> 16) != HCAN) &
        ((v.y & 0xffffu) != HCAN) & ((v.y >> 16) != HCAN))
      break;
    __builtin_amdgcn_s_sleep(1);
  }
  return v;
}

// ---------------------------------------------------------------------------
// canary fill for fp16 slabs 1..5
// ---------------------------------------------------------------------------
__global__ __launch_bounds__(256) void fill_canary(u32* __restrict__ p, long n) {
  long i = ((long)blockIdx.x * 256 + threadIdx.x) * 4;
  const long stride = (long)gridDim.x * 256 * 4;
  uint4 c;
  c.x = DCAN; c.y = DCAN; c.z = DCAN; c.w = DCAN;
  for (; i < n; i += stride) *(uint4*)(p + i) = c;
}

// ---------------------------------------------------------------------------
// lin1: slab0[t][h] = fp16( lines[t] . w1[h] + b1[h] )
// ---------------------------------------------------------------------------
__global__ __launch_bounds__(256) void lin1_kernel(
    const float* __restrict__ x, const float* __restrict__ w1,
    const float* __restrict__ b1, __half* __restrict__ X0) {
  __shared__ float lt[32][65];
  __shared__ float wt[128][65];
  const int tid = threadIdx.x;
  const int t0 = blockIdx.x * 32;
  const int h0 = blockIdx.y * 128;
  const int tt0 = (tid & 7) * 4;
  const int hh0 = (tid >> 3) * 4;
  float acc[4][4] = {};
  for (int kc = 0; kc < 512; kc += 64) {
    __syncthreads();
#pragma unroll
    for (int m = 0; m < 8; ++m) {
      int e = tid + m * 256;
      int tt = e >> 6, kk = e & 63;
      int k = kc + kk;
      int a = k >> 5, io = k & 31;
      int d = (a == 0) ? 0 : (a + 1);
      int st = t0 + tt - d;
      lt[tt][kk] = (st >= 0) ? x[st * 32 + io] : 0.f;
    }
#pragma unroll
    for (int m = 0; m < 32; ++m) {
      int e = tid + m * 256;
      int hh = e >> 6, kk = e & 63;
      wt[hh][kk] = w1[(size_t)(h0 + hh) * 512 + kc + kk];
    }
    __syncthreads();
    for (int kk = 0; kk < 64; ++kk) {
      float la[4], wa[4];
#pragma unroll
      for (int i = 0; i < 4; ++i) la[i] = lt[tt0 + i][kk];
#pragma unroll
      for (int j = 0; j < 4; ++j) wa[j] = wt[hh0 + j][kk];
#pragma unroll
      for (int i = 0; i < 4; ++i)
#pragma unroll
        for (int j = 0; j < 4; ++j) acc[i][j] = fmaf(la[i], wa[j], acc[i][j]);
    }
  }
#pragma unroll
  for (int i = 0; i < 4; ++i)
#pragma unroll
    for (int j = 0; j < 4; ++j)
      X0[(size_t)(t0 + tt0 + i) * HID + h0 + hh0 + j] =
          __float2half_rn(acc[i][j] + b1[h0 + hh0 + j]);
}

// ---------------------------------------------------------------------------
// persistent GRU pipeline: 5 stages x 51 blocks. fp16 weights register-resident.
// Split schedule: gi dots (x-only) fill the h-RTT shadow; post-detect work is
// only gh dots + reduce + gates. All activations fp16, canary-carried validity.
// ---------------------------------------------------------------------------
__global__ __launch_bounds__(512, 2) void gru_pipe(
    const float* __restrict__ wih, const float* __restrict__ whh,
    const float* __restrict__ bih, const float* __restrict__ bhh,
    __half* __restrict__ Xh) {
  const int bid = blockIdx.x;
  const int l   = bid / GSTAGE;
  const int bs  = bid % GSTAGE;
  const int tid = (int)threadIdx.x;
  const int lane = tid & 63;
  const int wv   = tid >> 6;           // 0..7
  const int half = lane >> 5;
  const int kc   = lane & 31;
  const int RG   = 2 * wv + half;      // 0..15 row-group

  const int h_base = (bs * HID) / GSTAGE;
  const int h_cnt  = ((bs + 1) * HID) / GSTAGE - h_base;   // 20 or 21
  const int ndot = 3 * h_cnt;                              // <= 63

  // --- weights: 4 gi rows + 4 gh rows, 32 k each, fp16 packed (128 regs) ---
  const size_t lw = (size_t)l * 3 * HID * HID;
  u32 wA[4][16], wB[4][16];
#pragma unroll
  for (int r = 0; r < 4; ++r) {
    const int d = 4 * RG + r;
    if (d < ndot) {
      const int jj = d / 3, g = d % 3;
      const float* rowA = wih + lw + (size_t)(g * HID + h_base + jj) * HID;
      const float* rowB = whh + lw + (size_t)(g * HID + h_base + jj) * HID;
#pragma unroll
      for (int s = 0; s < 4; ++s) {
        const float4* sa = (const float4*)(rowA + kc * 8 + s * 256);
        const float4* sb = (const float4*)(rowB + kc * 8 + s * 256);
        float4 a0 = sa[0], a1 = sa[1], b0 = sb[0], b1v = sb[1];
        wA[r][s * 4 + 0] = pkh(a0.x, a0.y);
        wA[r][s * 4 + 1] = pkh(a0.z, a0.w);
        wA[r][s * 4 + 2] = pkh(a1.x, a1.y);
        wA[r][s * 4 + 3] = pkh(a1.z, a1.w);
        wB[r][s * 4 + 0] = pkh(b0.x, b0.y);
        wB[r][s * 4 + 1] = pkh(b0.z, b0.w);
        wB[r][s * 4 + 2] = pkh(b1v.x, b1v.y);
        wB[r][s * 4 + 3] = pkh(b1v.z, b1v.w);
      }
    } else {
#pragma unroll
      for (int i = 0; i < 16; ++i) { wA[r][i] = 0u; wB[r][i] = 0u; }
    }
  }

  float b6[6] = {0.f, 0.f, 0.f, 0.f, 0.f, 0.f};
  if (wv == 0 && lane < h_cnt) {
#pragma unroll
    for (int g = 0; g < 3; ++g) {
      b6[g]     = bih[(size_t)l * 3 * HID + g * HID + h_base + lane];
      b6[3 + g] = bhh[(size_t)l * 3 * HID + g * HID + h_base + lane];
    }
  }

  __shared__ __align__(16) __half xbuf[2][HID];
  __shared__ __align__(16) __half hbuf[2][HID];
  __shared__ __align__(16) float scr[2][128];

  const __half* in = Xh + (size_t)l * TSTEPS * HID;        // x slab (layer input)
  __half* out      = Xh + (size_t)(l + 1) * TSTEPS * HID;  // h slab (layer output)

  // --- prologue: stage x_0 into xbuf[0] (waves 4-7) ---
  if (wv >= 4) {
    const int i = tid - 256;
    uint2 v;
    if (l == 0) v = *(const uint2*)(in + 4 * i);
    else        v = spin_load8(in + 4 * i);
    ((uint2*)xbuf[0])[i] = v;
  }
  float hprev = 0.f;   // wave-0 lanes: own fp32 h slice carried in register
  __syncthreads();

  for (int t = 0; t < TSTEPS; ++t) {
    const int p = t & 1;

    // ---- (a) gi dots from xbuf[p] — off the h critical path ----
    {
      const uint4* cp = (const uint4*)xbuf[p];
      float a0 = 0.f, a1 = 0.f, a2 = 0.f, a3 = 0.f;
#pragma unroll
      for (int s = 0; s < 4; ++s) {
        uint4 c = cp[kc + 32 * s];
        a0 = fdot2f(wA[0][4 * s + 0], c.x, a0);
        a1 = fdot2f(wA[1][4 * s + 0], c.x, a1);
        a2 = fdot2f(wA[2][4 * s + 0], c.x, a2);
        a3 = fdot2f(wA[3][4 * s + 0], c.x, a3);
        a0 = fdot2f(wA[0][4 * s + 1], c.y, a0);
        a1 = fdot2f(wA[1][4 * s + 1], c.y, a1);
        a2 = fdot2f(wA[2][4 * s + 1], c.y, a2);
        a3 = fdot2f(wA[3][4 * s + 1], c.y, a3);
        a0 = fdot2f(wA[0][4 * s + 2], c.z, a0);
        a1 = fdot2f(wA[1][4 * s + 2], c.z, a1);
        a2 = fdot2f(wA[2][4 * s + 2], c.z, a2);
        a3 = fdot2f(wA[3][4 * s + 2], c.z, a3);
        a0 = fdot2f(wA[0][4 * s + 3], c.w, a0);
        a1 = fdot2f(wA[1][4 * s + 3], c.w, a1);
        a2 = fdot2f(wA[2][4 * s + 3], c.w, a2);
        a3 = fdot2f(wA[3][4 * s + 3], c.w, a3);
      }
      a0 = dpp_red32(a0);
      a1 = dpp_red32(a1);
      a2 = dpp_red32(a2);
      a3 = dpp_red32(a3);
      if ((lane & 31) == 31) {
        float4 s4; s4.x = a0; s4.y = a1; s4.z = a2; s4.w = a3;
        *((float4*)&scr[p][4 * RG]) = s4;
      }
    }

    // ---- (b) waves 0-3: spin-stage h_{t-1}; waves 4-7: prefetch x_{t+1} ----
    if (wv < 4) {
      if (t > 0) {
        uint2 v = spin_load8(out + (size_t)(t - 1) * HID + 4 * tid);
        ((uint2*)hbuf[p])[tid] = v;
      } else {
        uint2 z; z.x = 0u; z.y = 0u;
        ((uint2*)hbuf[p])[tid] = z;
      }
    } else {
      const int i = tid - 256;
      const int tn = (t + 1 < TSTEPS) ? (t + 1) : (TSTEPS - 1);
      uint2 v;
      if (l == 0) v = *(const uint2*)(in + (size_t)tn * HID + 4 * i);
      else        v = spin_load8(in + (size_t)tn * HID + 4 * i);
      ((uint2*)xbuf[p ^ 1])[i] = v;
    }
    __syncthreads();   // (c)

    // ---- gh dots from hbuf[p] — the only dot work on the critical path ----
    {
      const uint4* cp = (const uint4*)hbuf[p];
      float a0 = 0.f, a1 = 0.f, a2 = 0.f, a3 = 0.f;
#pragma unroll
      for (int s = 0; s < 4; ++s) {
        uint4 c = cp[kc + 32 * s];
        a0 = fdot2f(wB[0][4 * s + 0], c.x, a0);
        a1 = fdot2f(wB[1][4 * s + 0], c.x, a1);
        a2 = fdot2f(wB[2][4 * s + 0], c.x, a2);
        a3 = fdot2f(wB[3][4 * s + 0], c.x, a3);
        a0 = fdot2f(wB[0][4 * s + 1], c.y, a0);
        a1 = fdot2f(wB[1][4 * s + 1], c.y, a1);
        a2 = fdot2f(wB[2][4 * s + 1], c.y, a2);
        a3 = fdot2f(wB[3][4 * s + 1], c.y, a3);
        a0 = fdot2f(wB[0][4 * s + 2], c.z, a0);
        a1 = fdot2f(wB[1][4 * s + 2], c.z, a1);
        a2 = fdot2f(wB[2][4 * s + 2], c.z, a2);
        a3 = fdot2f(wB[3][4 * s + 2], c.z, a3);
        a0 = fdot2f(wB[0][4 * s + 3], c.w, a0);
        a1 = fdot2f(wB[1][4 * s + 3], c.w, a1);
        a2 = fdot2f(wB[2][4 * s + 3], c.w, a2);
        a3 = fdot2f(wB[3][4 * s + 3], c.w, a3);
      }
      a0 = dpp_red32(a0);
      a1 = dpp_red32(a1);
      a2 = dpp_red32(a2);
      a3 = dpp_red32(a3);
      if ((lane & 31) == 31) {
        float4 s4; s4.x = a0; s4.y = a1; s4.z = a2; s4.w = a3;
        *((float4*)&scr[p][64 + 4 * RG]) = s4;
      }
    }
    __syncthreads();   // (d)

    // ---- (e) gates on wave 0; publish h_t as fp16, LLC-direct ----
    if (wv == 0 && lane < h_cnt) {
      const int jj = lane;
      float ir = scr[p][3 * jj + 0] + b6[0];
      float iz = scr[p][3 * jj + 1] + b6[1];
      float in_ = scr[p][3 * jj + 2] + b6[2];
      float hr = scr[p][64 + 3 * jj + 0] + b6[3];
      float hz = scr[p][64 + 3 * jj + 1] + b6[4];
      float hn = scr[p][64 + 3 * jj + 2] + b6[5];
      float rr = 1.f / (1.f + __expf(-(ir + hr)));
      float zz = 1.f / (1.f + __expf(-(iz + hz)));
      float targ = in_ + rr * hn;
      targ = fminf(fmaxf(targ, -15.f), 15.f);
      float e2 = __expf(2.f * targ);
      float nn = (e2 - 1.f) / (e2 + 1.f);
      float hv = (1.f - zz) * nn + zz * hprev;
      hprev = hv;
      u32 hb = (u32)__half_as_ushort(__float2half_rn(hv));
      const __half* dst = out + (size_t)t * HID + h_base + jj;
      asm volatile("global_store_short %0, %1, off sc0 sc1" :: "v"(dst), "v"(hb));
    }
  }
}

// ---------------------------------------------------------------------------
// lin2: out[o,t,io] = h5[t] . w2[o*32+io] + b2   (h5 fp16)
// ---------------------------------------------------------------------------
__global__ __launch_bounds__(256) void lin2_kernel(
    const __half* __restrict__ h5, const float* __restrict__ w2,
    const float* __restrict__ b2, float* __restrict__ out) {
  __shared__ float at[64][65];
  __shared__ float bt[64][65];
  const int tid = threadIdx.x;
  const int t0 = blockIdx.x * 64;
  const int j0 = blockIdx.y * 64;
  const int tt0 = (tid & 15) * 4;
  const int jj0 = (tid >> 4) * 4;
  float acc[4][4] = {};
  for (int kc = 0; kc < 1024; kc += 64) {
    __syncthreads();
#pragma unroll
    for (int m = 0; m < 16; ++m) {
      int e = tid + m * 256;
      int tt = e >> 6, kk = e & 63;
      at[tt][kk] = __half2float(h5[(size_t)(t0 + tt) * HID + kc + kk]);
    }
#pragma unroll
    for (int m = 0; m < 16; ++m) {
      int e = tid + m * 256;
      int jj = e >> 6, kk = e & 63;
      bt[jj][kk] = w2[(size_t)(j0 + jj) * HID + kc + kk];
    }
    __syncthreads();
    for (int kk = 0; kk < 64; ++kk) {
      float la[4], wa[4];
#pragma unroll
      for (int i = 0; i < 4; ++i) la[i] = at[tt0 + i][kk];
#pragma unroll
      for (int j = 0; j < 4; ++j) wa[j] = bt[jj0 + j][kk];
#pragma unroll
      for (int i = 0; i < 4; ++i)
#pragma unroll
        for (int j = 0; j < 4; ++j) acc[i][j] = fmaf(la[i], wa[j], acc[i][j]);
    }
  }
#pragma unroll
  for (int i = 0; i < 4; ++i)
#pragma unroll
    for (int jq = 0; jq < 4; ++jq) {
      int j = j0 + jj0 + jq;
      out[(size_t)(j >> 5) * (TSTEPS * 32) + (size_t)(t0 + tt0 + i) * 32 + (j & 31)] =
          acc[i][jq] + b2[j];
    }
}

extern "C" void kernel_launch(void* const* d_in, const int* in_sizes, int n_in,
                              void* d_out, int out_size, void* d_ws, size_t ws_size,
                              hipStream_t stream) {
  const float* x   = (const float*)d_in[0];
  const float* w1  = (const float*)d_in[1];
  const float* b1  = (const float*)d_in[2];
  const float* wih = (const float*)d_in[3];
  const float* whh = (const float*)d_in[4];
  const float* bih = (const float*)d_in[5];
  const float* bhh = (const float*)d_in[6];
  const float* w2  = (const float*)d_in[7];
  const float* b2  = (const float*)d_in[8];
  float* out = (float*)d_out;

  __half* Xh = (__half*)d_ws;  // 6 fp16 slabs of [T][H] (25.2 MB)

  // arm canaries in slabs 1..5 (re-armed every launch/replay)
  fill_canary<<<1280, 256, 0, stream>>>((u32*)(Xh + (size_t)TSTEPS * HID),
                                        (long)NDEPTH * TSTEPS * HID / 2);
  lin1_kernel<<<dim3(64, 8), 256, 0, stream>>>(x, w1, b1, Xh);
  gru_pipe<<<NBLOCKS, 512, 0, stream>>>(wih, whh, bih, bhh, Xh);
  lin2_kernel<<<dim3(32, 4), 256, 0, stream>>>(Xh + (size_t)NDEPTH * TSTEPS * HID,
                                               w2, b2, out);
}